// Round 1
// baseline (600.588 us; speedup 1.0000x reference)
//
#include <hip/hip_runtime.h>
#include <stdint.h>

#define DI __device__ __forceinline__

using floatx4 = __attribute__((ext_vector_type(4))) float;
using short8  = __attribute__((ext_vector_type(8))) short;   // 8 bf16 in 4 VGPRs

DI uint16_t f2b(float f) {  // fp32 -> bf16 round-to-nearest-even
  uint32_t u = __float_as_uint(f);
  return (uint16_t)((u + 0x7FFFu + ((u >> 16) & 1u)) >> 16);
}

DI void async_cp16(const uint16_t* g, uint16_t* l) {
  // 16B per lane, LDS dest = wave-uniform base + lane*16 (no padding allowed)
  __builtin_amdgcn_global_load_lds(
      (const __attribute__((address_space(1))) void*)g,
      (__attribute__((address_space(3))) void*)l, 16, 0, 0);
}

// ---------------------------------------------------------------- X fp32->bf16
__global__ __launch_bounds__(256)
void cvt_bf16(const float* __restrict__ x, uint16_t* __restrict__ y) {
  long i = ((long)blockIdx.x * 256 + threadIdx.x) * 8;
  float4 a = *(const float4*)(x + i);
  float4 b = *(const float4*)(x + i + 4);
  union { uint16_t u[8]; uint4 v; } o;
  o.u[0] = f2b(a.x); o.u[1] = f2b(a.y); o.u[2] = f2b(a.z); o.u[3] = f2b(a.w);
  o.u[4] = f2b(b.x); o.u[5] = f2b(b.y); o.u[6] = f2b(b.z); o.u[7] = f2b(b.w);
  *(uint4*)(y + i) = o.v;
}

// ------------------------------------------------- T1[(ijkl)][b] = g0 x g1
// T1 as (ij)x(klb) matrix: T1[ij*16384 + klb] = sum_a g0[ij*64+a]*g1[a*16384+klb]
// grid (4 rowchunks of 64, 128 colchunks of 128), block 256
__global__ __launch_bounds__(256)
void tt_t1(const float* __restrict__ g0, const float* __restrict__ g1,
           uint16_t* __restrict__ t1) {
  __shared__ float g0s[64 * 64];    // [row][a]  16KB
  __shared__ float g1s[64 * 128];   // [a][col]  32KB
  const int rowbase = blockIdx.x * 64;
  const int colbase = blockIdx.y * 128;
  const int t = threadIdx.x;

  for (int f = t; f < 4096; f += 256) g0s[f] = g0[rowbase * 64 + f];
  for (int f = t; f < 8192; f += 256) {
    int a = f >> 7, c = f & 127;
    g1s[f] = g1[(long)a * 16384 + colbase + c];
  }
  __syncthreads();

  const int tx = t & 31;        // col group: 32 x 4 cols = 128
  const int ty = t >> 5;        // row group: 8 x 8 rows = 64
  const int c0 = tx * 4;
  const int r0 = ty * 8;

  float acc[8][4];
  #pragma unroll
  for (int r = 0; r < 8; ++r)
    #pragma unroll
    for (int c = 0; c < 4; ++c) acc[r][c] = 0.f;

  for (int a4 = 0; a4 < 16; ++a4) {
    float g0r[8][4];
    #pragma unroll
    for (int r = 0; r < 8; ++r)
      *(float4*)&g0r[r][0] = *(const float4*)&g0s[(r0 + r) * 64 + a4 * 4];
    #pragma unroll
    for (int e = 0; e < 4; ++e) {
      float4 bv4 = *(const float4*)&g1s[(a4 * 4 + e) * 128 + c0];
      float bv[4] = {bv4.x, bv4.y, bv4.z, bv4.w};
      #pragma unroll
      for (int r = 0; r < 8; ++r)
        #pragma unroll
        for (int c = 0; c < 4; ++c)
          acc[r][c] += g0r[r][e] * bv[c];
    }
  }

  #pragma unroll
  for (int r = 0; r < 8; ++r) {
    ushort4 o;
    o.x = f2b(acc[r][0]); o.y = f2b(acc[r][1]);
    o.z = f2b(acc[r][2]); o.w = f2b(acc[r][3]);
    *(ushort4*)&t1[(long)(rowbase + r0 + r) * 16384 + colbase + c0] = o;
  }
}

// ------------------------------------------------- g2t[(mn)][b] = g2[b][(mn)]
__global__ __launch_bounds__(256)
void g2t_build(const float* __restrict__ g2, uint16_t* __restrict__ g2t) {
  int f = blockIdx.x * 256 + threadIdx.x;   // 0..16383
  int mn = f >> 6, b = f & 63;
  g2t[f] = f2b(g2[b * 256 + mn]);
}

// ------------------------------------------------- m97-style GEMM, Bt = B^T
// C[m][n] = sum_k A[m][k] * Bt[n][k] (+ bias[n]); 128x128 tile, BK=32, 4 waves 2x2
// A row stride = K; Bt row stride = ldB; per-z offsets zB (Bt elems), zC (C elems)
template <bool OUT_BF16, bool ADD_BIAS>
__global__ __launch_bounds__(256)
void gemm_bt(const uint16_t* __restrict__ A, const uint16_t* __restrict__ Bt,
             void* __restrict__ Cv, const float* __restrict__ bias,
             int K, int N, int ldB, long zB, long zC) {
  __shared__ __align__(16) uint16_t As[128 * 32];   // 8KB, no padding (global_load_lds)
  __shared__ __align__(16) uint16_t Bs[128 * 32];   // 8KB

  const int bm = blockIdx.x * 128;
  const int bn = blockIdx.y * 128;
  const int tid  = threadIdx.x;
  const int wave = tid >> 6;
  const int lane = tid & 63;
  const int wm = (wave >> 1) * 64;
  const int wn = (wave & 1) * 64;

  const uint16_t* Ab = A + (long)bm * K;
  const uint16_t* Bb = Bt + (long)bn * ldB + zB * blockIdx.z;

  const int srow = lane >> 2;        // staging: 16 rows x 64B per wave-issue
  const int scol = (lane & 3) * 8;

  floatx4 acc[4][4];
  #pragma unroll
  for (int i = 0; i < 4; ++i)
    #pragma unroll
    for (int j = 0; j < 4; ++j)
      acc[i][j] = (floatx4){0.f, 0.f, 0.f, 0.f};

  const int fr = lane & 15;          // fragment row (m or n)
  const int fk = (lane >> 4) * 8;    // fragment k offset

  for (int k0 = 0; k0 < K; k0 += 32) {
    __syncthreads();                 // previous compute done before LDS overwrite
    #pragma unroll
    for (int t = 0; t < 2; ++t) {
      const int rblk = wave * 2 + t; // 0..7, 16 rows each
      async_cp16(Ab + (long)(rblk * 16 + srow) * K   + k0 + scol, &As[rblk * 16 * 32]);
      async_cp16(Bb + (long)(rblk * 16 + srow) * ldB + k0 + scol, &Bs[rblk * 16 * 32]);
    }
    __syncthreads();                 // compiler drains vmcnt before barrier

    short8 af[4], bg[4];
    #pragma unroll
    for (int i = 0; i < 4; ++i)
      af[i] = *(const short8*)&As[(wm + i * 16 + fr) * 32 + fk];
    #pragma unroll
    for (int j = 0; j < 4; ++j)
      bg[j] = *(const short8*)&Bs[(wn + j * 16 + fr) * 32 + fk];

    #pragma unroll
    for (int i = 0; i < 4; ++i)
      #pragma unroll
      for (int j = 0; j < 4; ++j)
        acc[i][j] = __builtin_amdgcn_mfma_f32_16x16x32_bf16(af[i], bg[j], acc[i][j], 0, 0, 0);
  }

  const int colq = lane & 15;
  const int rowq = (lane >> 4) * 4;
  const long cbase = zC * blockIdx.z;
  #pragma unroll
  for (int j = 0; j < 4; ++j) {
    const int col = bn + wn + j * 16 + colq;
    float bv = 0.f;
    if constexpr (ADD_BIAS) bv = bias[col];
    #pragma unroll
    for (int i = 0; i < 4; ++i)
      #pragma unroll
      for (int r = 0; r < 4; ++r) {
        const int row = bm + wm + i * 16 + rowq + r;
        float v = acc[i][j][r] + bv;
        if constexpr (OUT_BF16)
          ((uint16_t*)Cv)[cbase + (long)row * N + col] = f2b(v);
        else
          ((float*)Cv)[cbase + (long)row * N + col] = v;
      }
  }
}

// ---------------------------------------------------------------- launch
// ws layout (bytes): Xbf 64MB @0 | Gt 32MB @64M | T1 8MB @96M | g2t 32KB @104M
static constexpr long XBF_OFF = 0;
static constexpr long GT_OFF  = 67108864;
static constexpr long T1_OFF  = 100663296;
static constexpr long G2T_OFF = 109051904;

extern "C" void kernel_launch(void* const* d_in, const int* in_sizes, int n_in,
                              void* d_out, int out_size, void* d_ws, size_t ws_size,
                              hipStream_t stream) {
  const float* x    = (const float*)d_in[0];
  const float* g0   = (const float*)d_in[1];
  const float* g1   = (const float*)d_in[2];
  const float* g2   = (const float*)d_in[3];
  const float* bias = (const float*)d_in[4];
  float* out = (float*)d_out;

  char* ws = (char*)d_ws;
  uint16_t* Xbf = (uint16_t*)(ws + XBF_OFF);
  uint16_t* Gt  = (uint16_t*)(ws + GT_OFF);
  uint16_t* T1  = (uint16_t*)(ws + T1_OFF);
  uint16_t* G2T = (uint16_t*)(ws + G2T_OFF);

  // 1) X -> bf16 (33.5M elems, 8/thread)
  cvt_bf16<<<16384, 256, 0, stream>>>(x, Xbf);
  // 2) T1[(ijkl)][b] bf16
  tt_t1<<<dim3(4, 128), 256, 0, stream>>>(g0, g1, T1);
  // 3) g2t[(mn)][b] bf16
  g2t_build<<<64, 256, 0, stream>>>(g2, G2T);
  // 4) Gt[(l*256+mn)][(ijk)] = sum_b g2t[mn][b] * T1[(ijk*16+l)][b]
  //    16 sub-GEMMs (z=l): M=256, N=4096, K=64; Bt=T1 ldB=1024, zB=64, zC=256*4096
  gemm_bt<true, false><<<dim3(2, 32, 16), 256, 0, stream>>>(
      G2T, T1, (void*)Gt, nullptr, 64, 4096, 1024, 64L, 1048576L);
  // 5) out = Xbf @ Gt^T + bias: M=8192, N=4096, K=4096
  gemm_bt<false, true><<<dim3(64, 32, 1), 256, 0, stream>>>(
      Xbf, Gt, (void*)out, bias, 4096, 4096, 4096, 0L, 0L);
}

// Round 2
// 385.898 us; speedup vs baseline: 1.5563x; 1.5563x over previous
//
#include <hip/hip_runtime.h>
#include <stdint.h>

#define DI __device__ __forceinline__

using floatx4 = __attribute__((ext_vector_type(4))) float;
using short8  = __attribute__((ext_vector_type(8))) short;   // 8 bf16 in 4 VGPRs

DI uint16_t f2b(float f) {  // fp32 -> bf16 round-to-nearest-even
  uint32_t u = __float_as_uint(f);
  return (uint16_t)((u + 0x7FFFu + ((u >> 16) & 1u)) >> 16);
}

DI void async_cp16(const uint16_t* g, uint16_t* l) {
  // 16B per lane, LDS dest = wave-uniform base + lane*16 (no padding allowed)
  __builtin_amdgcn_global_load_lds(
      (const __attribute__((address_space(1))) void*)g,
      (__attribute__((address_space(3))) void*)l, 16, 0, 0);
}

// ---------------------------------------------------------------- X fp32->bf16
__global__ __launch_bounds__(256)
void cvt_bf16(const float* __restrict__ x, uint16_t* __restrict__ y) {
  long i = ((long)blockIdx.x * 256 + threadIdx.x) * 8;
  float4 a = *(const float4*)(x + i);
  float4 b = *(const float4*)(x + i + 4);
  union { uint16_t u[8]; uint4 v; } o;
  o.u[0] = f2b(a.x); o.u[1] = f2b(a.y); o.u[2] = f2b(a.z); o.u[3] = f2b(a.w);
  o.u[4] = f2b(b.x); o.u[5] = f2b(b.y); o.u[6] = f2b(b.z); o.u[7] = f2b(b.w);
  *(uint4*)(y + i) = o.v;
}

// ------------------------------------------------- T1[(ijkl)][b] = g0 x g1
// T1 as (ij)x(klb) matrix: T1[ij*16384 + klb] = sum_a g0[ij*64+a]*g1[a*16384+klb]
// Identical memory layout to [(ijk)][(lb)] row-major 4096x1024.
__global__ __launch_bounds__(256)
void tt_t1(const float* __restrict__ g0, const float* __restrict__ g1,
           uint16_t* __restrict__ t1) {
  __shared__ float g0s[64 * 64];    // [row][a]  16KB
  __shared__ float g1s[64 * 128];   // [a][col]  32KB
  const int rowbase = blockIdx.x * 64;
  const int colbase = blockIdx.y * 128;
  const int t = threadIdx.x;

  for (int f = t; f < 4096; f += 256) g0s[f] = g0[rowbase * 64 + f];
  for (int f = t; f < 8192; f += 256) {
    int a = f >> 7, c = f & 127;
    g1s[f] = g1[(long)a * 16384 + colbase + c];
  }
  __syncthreads();

  const int tx = t & 31;
  const int ty = t >> 5;
  const int c0 = tx * 4;
  const int r0 = ty * 8;

  float acc[8][4];
  #pragma unroll
  for (int r = 0; r < 8; ++r)
    #pragma unroll
    for (int c = 0; c < 4; ++c) acc[r][c] = 0.f;

  for (int a4 = 0; a4 < 16; ++a4) {
    float g0r[8][4];
    #pragma unroll
    for (int r = 0; r < 8; ++r)
      *(float4*)&g0r[r][0] = *(const float4*)&g0s[(r0 + r) * 64 + a4 * 4];
    #pragma unroll
    for (int e = 0; e < 4; ++e) {
      float4 bv4 = *(const float4*)&g1s[(a4 * 4 + e) * 128 + c0];
      float bv[4] = {bv4.x, bv4.y, bv4.z, bv4.w};
      #pragma unroll
      for (int r = 0; r < 8; ++r)
        #pragma unroll
        for (int c = 0; c < 4; ++c)
          acc[r][c] += g0r[r][e] * bv[c];
    }
  }

  #pragma unroll
  for (int r = 0; r < 8; ++r) {
    ushort4 o;
    o.x = f2b(acc[r][0]); o.y = f2b(acc[r][1]);
    o.z = f2b(acc[r][2]); o.w = f2b(acc[r][3]);
    *(ushort4*)&t1[(long)(rowbase + r0 + r) * 16384 + colbase + c0] = o;
  }
}

// ------------------------------------------------- g2t[(mn)][b] = g2[b][(mn)]
__global__ __launch_bounds__(256)
void g2t_build(const float* __restrict__ g2, uint16_t* __restrict__ g2t) {
  int f = blockIdx.x * 256 + threadIdx.x;   // 0..16383
  int mn = f >> 6, b = f & 63;
  g2t[f] = f2b(g2[b * 256 + mn]);
}

// ------------------------------------------------- T1 (4096x1024) -> T1t (1024x4096)
// LDS-tiled transpose, both sides ushort4-coalesced. 64x64 tiles.
__global__ __launch_bounds__(256)
void transpose_t1(const uint16_t* __restrict__ src, uint16_t* __restrict__ dst) {
  __shared__ uint16_t tile[64][68];   // pad keeps 8B align (68*2=136=17*8)
  const int cb = blockIdx.x * 64;     // col tile in src (lb dim, 1024)
  const int rb = blockIdx.y * 64;     // row tile in src (ijk dim, 4096)
  const int t = threadIdx.x;
  {
    const int c4 = (t & 15) * 4;
    const int r  = t >> 4;
    #pragma unroll
    for (int p = 0; p < 4; ++p) {
      int rr = r + p * 16;
      *(ushort4*)&tile[rr][c4] = *(const ushort4*)&src[(long)(rb + rr) * 1024 + cb + c4];
    }
  }
  __syncthreads();
  {
    const int r4 = (t & 15) * 4;
    const int c  = t >> 4;
    #pragma unroll
    for (int p = 0; p < 4; ++p) {
      int cc = c + p * 16;
      ushort4 o;
      o.x = tile[r4 + 0][cc]; o.y = tile[r4 + 1][cc];
      o.z = tile[r4 + 2][cc]; o.w = tile[r4 + 3][cc];
      *(ushort4*)&dst[(long)(cb + cc) * 4096 + rb + r4] = o;
    }
  }
}

// ------------------------------------------------- m97-style GEMM, Bt = B^T
// C[m][n] = sum_k A[m][k+zA*z] * Bt[n][k] (+ bias); 128x128 tile, BK=32, 4 waves 2x2
// C index = row*ldC + colOff*z + col; bias[colOff*z + col].
template <bool OUT_BF16, bool ADD_BIAS>
__global__ __launch_bounds__(256)
void gemm_bt(const uint16_t* __restrict__ A, int ldA, int zA,
             const uint16_t* __restrict__ Bt, int ldB,
             void* __restrict__ Cv, int ldC, int colOff,
             const float* __restrict__ bias, int K) {
  __shared__ __align__(16) uint16_t As[128 * 32];   // 8KB, no padding (global_load_lds)
  __shared__ __align__(16) uint16_t Bs[128 * 32];   // 8KB

  const int bm = blockIdx.x * 128;
  const int bn = blockIdx.y * 128;
  const int z  = blockIdx.z;
  const int tid  = threadIdx.x;
  const int wave = tid >> 6;
  const int lane = tid & 63;
  const int wm = (wave >> 1) * 64;
  const int wn = (wave & 1) * 64;

  const uint16_t* Ab = A + (long)bm * ldA + (long)zA * z;
  const uint16_t* Bb = Bt + (long)bn * ldB;

  const int srow = lane >> 2;        // staging: 16 rows x 64B per wave-issue
  const int scol = (lane & 3) * 8;

  floatx4 acc[4][4];
  #pragma unroll
  for (int i = 0; i < 4; ++i)
    #pragma unroll
    for (int j = 0; j < 4; ++j)
      acc[i][j] = (floatx4){0.f, 0.f, 0.f, 0.f};

  const int fr = lane & 15;          // fragment row (m or n)
  const int fk = (lane >> 4) * 8;    // fragment k offset

  for (int k0 = 0; k0 < K; k0 += 32) {
    __syncthreads();
    #pragma unroll
    for (int t = 0; t < 2; ++t) {
      const int rblk = wave * 2 + t; // 0..7, 16 rows each
      async_cp16(Ab + (long)(rblk * 16 + srow) * ldA + k0 + scol, &As[rblk * 16 * 32]);
      async_cp16(Bb + (long)(rblk * 16 + srow) * ldB + k0 + scol, &Bs[rblk * 16 * 32]);
    }
    __syncthreads();

    short8 af[4], bg[4];
    #pragma unroll
    for (int i = 0; i < 4; ++i)
      af[i] = *(const short8*)&As[(wm + i * 16 + fr) * 32 + fk];
    #pragma unroll
    for (int j = 0; j < 4; ++j)
      bg[j] = *(const short8*)&Bs[(wn + j * 16 + fr) * 32 + fk];

    #pragma unroll
    for (int i = 0; i < 4; ++i)
      #pragma unroll
      for (int j = 0; j < 4; ++j)
        acc[i][j] = __builtin_amdgcn_mfma_f32_16x16x32_bf16(af[i], bg[j], acc[i][j], 0, 0, 0);
  }

  const int colq = lane & 15;
  const int rowq = (lane >> 4) * 4;
  const long coff = (long)colOff * z;
  #pragma unroll
  for (int j = 0; j < 4; ++j) {
    const int col = bn + wn + j * 16 + colq;
    float bv = 0.f;
    if constexpr (ADD_BIAS) bv = bias[coff + col];
    #pragma unroll
    for (int i = 0; i < 4; ++i)
      #pragma unroll
      for (int r = 0; r < 4; ++r) {
        const int row = bm + wm + i * 16 + rowq + r;
        float v = acc[i][j][r] + bv;
        if constexpr (OUT_BF16)
          ((uint16_t*)Cv)[(long)row * ldC + coff + col] = f2b(v);
        else
          ((float*)Cv)[(long)row * ldC + coff + col] = v;
      }
  }
}

// ---------------------------------------------------------------- launch
// ws layout (bytes): Xbf 64MB | T1 8MB | T1t 8MB | V 16MB | g2t 32KB  (~100.7MB)
static constexpr long XBF_OFF = 0;
static constexpr long T1_OFF  = 67108864;
static constexpr long T1T_OFF = 75497472;
static constexpr long V_OFF   = 83886080;
static constexpr long G2T_OFF = 100663296;

extern "C" void kernel_launch(void* const* d_in, const int* in_sizes, int n_in,
                              void* d_out, int out_size, void* d_ws, size_t ws_size,
                              hipStream_t stream) {
  const float* x    = (const float*)d_in[0];
  const float* g0   = (const float*)d_in[1];
  const float* g1   = (const float*)d_in[2];
  const float* g2   = (const float*)d_in[3];
  const float* bias = (const float*)d_in[4];
  float* out = (float*)d_out;

  char* ws = (char*)d_ws;
  uint16_t* Xbf = (uint16_t*)(ws + XBF_OFF);
  uint16_t* T1  = (uint16_t*)(ws + T1_OFF);
  uint16_t* T1t = (uint16_t*)(ws + T1T_OFF);
  uint16_t* V   = (uint16_t*)(ws + V_OFF);
  uint16_t* G2T = (uint16_t*)(ws + G2T_OFF);

  // 1) X -> bf16
  cvt_bf16<<<16384, 256, 0, stream>>>(x, Xbf);
  // 2) T1[(ijk)][(lb)] bf16, 4096x1024 row-major
  tt_t1<<<dim3(4, 128), 256, 0, stream>>>(g0, g1, T1);
  // 3) g2t[(mn)][b] bf16, 256x64
  g2t_build<<<64, 256, 0, stream>>>(g2, G2T);
  // 4) T1t[(lb)][(ijk)] = T1^T, 1024x4096 (k-contiguous B^T operand)
  transpose_t1<<<dim3(16, 64), 256, 0, stream>>>(T1, T1t);
  // 5) V = Xbf @ T1 (bf16 out): M=8192, N=1024, K=4096
  gemm_bt<true, false><<<dim3(64, 8, 1), 256, 0, stream>>>(
      Xbf, 4096, 0, T1t, 4096, (void*)V, 1024, 0, nullptr, 4096);
  // 6) out[s, l*256+mn] = sum_b V[s, l*64+b]*g2t[mn][b] + bias
  //    z=l: M=8192, N=256 (2 col-blocks), K=64
  gemm_bt<false, true><<<dim3(64, 2, 16), 256, 0, stream>>>(
      V, 1024, 64, G2T, 64, (void*)out, 4096, 256, bias, 64);
}

// Round 4
// 350.778 us; speedup vs baseline: 1.7122x; 1.1001x over previous
//
#include <hip/hip_runtime.h>
#include <stdint.h>

#define DI __device__ __forceinline__

using floatx4 = __attribute__((ext_vector_type(4))) float;
using short8  = __attribute__((ext_vector_type(8))) short;   // 8 bf16 in 4 VGPRs

DI uint16_t f2b(float f) {  // fp32 -> bf16 round-to-nearest-even
  uint32_t u = __float_as_uint(f);
  return (uint16_t)((u + 0x7FFFu + ((u >> 16) & 1u)) >> 16);
}

DI void async_cp16(const uint16_t* g, uint16_t* l) {
  // 16B per lane, LDS dest = wave-uniform base + lane*16 (no padding allowed)
  __builtin_amdgcn_global_load_lds(
      (const __attribute__((address_space(1))) void*)g,
      (__attribute__((address_space(3))) void*)l, 16, 0, 0);
}

// ---------------------------------------------------------------- X fp32->bf16
__global__ __launch_bounds__(256)
void cvt_bf16(const float* __restrict__ x, uint16_t* __restrict__ y) {
  long i = ((long)blockIdx.x * 256 + threadIdx.x) * 8;
  float4 a = *(const float4*)(x + i);
  float4 b = *(const float4*)(x + i + 4);
  union { uint16_t u[8]; uint4 v; } o;
  o.u[0] = f2b(a.x); o.u[1] = f2b(a.y); o.u[2] = f2b(a.z); o.u[3] = f2b(a.w);
  o.u[4] = f2b(b.x); o.u[5] = f2b(b.y); o.u[6] = f2b(b.z); o.u[7] = f2b(b.w);
  *(uint4*)(y + i) = o.v;
}

// ------------------------------------------------- T1[(ijkl)][b] = g0 x g1
// T1 as (ij)x(klb): T1[ij*16384 + klb] = sum_a g0[ij*64+a]*g1[a*16384+klb]
// Same memory as [(ijk)][(lb)] row-major 4096x1024.
__global__ __launch_bounds__(256)
void tt_t1(const float* __restrict__ g0, const float* __restrict__ g1,
           uint16_t* __restrict__ t1) {
  __shared__ float g0s[64 * 64];    // [row][a]  16KB
  __shared__ float g1s[64 * 128];   // [a][col]  32KB
  const int rowbase = blockIdx.x * 64;
  const int colbase = blockIdx.y * 128;
  const int t = threadIdx.x;

  for (int f = t; f < 4096; f += 256) g0s[f] = g0[rowbase * 64 + f];
  for (int f = t; f < 8192; f += 256) {
    int a = f >> 7, c = f & 127;
    g1s[f] = g1[(long)a * 16384 + colbase + c];
  }
  __syncthreads();

  const int tx = t & 31;
  const int ty = t >> 5;
  const int c0 = tx * 4;
  const int r0 = ty * 8;

  float acc[8][4];
  #pragma unroll
  for (int r = 0; r < 8; ++r)
    #pragma unroll
    for (int c = 0; c < 4; ++c) acc[r][c] = 0.f;

  for (int a4 = 0; a4 < 16; ++a4) {
    float g0r[8][4];
    #pragma unroll
    for (int r = 0; r < 8; ++r)
      *(float4*)&g0r[r][0] = *(const float4*)&g0s[(r0 + r) * 64 + a4 * 4];
    #pragma unroll
    for (int e = 0; e < 4; ++e) {
      float4 bv4 = *(const float4*)&g1s[(a4 * 4 + e) * 128 + c0];
      float bv[4] = {bv4.x, bv4.y, bv4.z, bv4.w};
      #pragma unroll
      for (int r = 0; r < 8; ++r)
        #pragma unroll
        for (int c = 0; c < 4; ++c)
          acc[r][c] += g0r[r][e] * bv[c];
    }
  }

  #pragma unroll
  for (int r = 0; r < 8; ++r) {
    ushort4 o;
    o.x = f2b(acc[r][0]); o.y = f2b(acc[r][1]);
    o.z = f2b(acc[r][2]); o.w = f2b(acc[r][3]);
    *(ushort4*)&t1[(long)(rowbase + r0 + r) * 16384 + colbase + c0] = o;
  }
}

// ------------------------------------------------- T1 (4096x1024) -> T1t (1024x4096)
// LDS-tiled transpose; blocks with y==0 also build g2t[(mn)][b] = g2[b][(mn)].
__global__ __launch_bounds__(256)
void transpose_t1(const uint16_t* __restrict__ src, uint16_t* __restrict__ dst,
                  const float* __restrict__ g2, uint16_t* __restrict__ g2t) {
  __shared__ uint16_t tile[64][68];
  const int cb = blockIdx.x * 64;     // col tile in src (lb dim, 1024)
  const int rb = blockIdx.y * 64;     // row tile in src (ijk dim, 4096)
  const int t = threadIdx.x;

  if (blockIdx.y == 0) {              // side job: 16 blocks x 1024 elems
    #pragma unroll
    for (int p = 0; p < 4; ++p) {
      int f = blockIdx.x * 1024 + p * 256 + t;   // 0..16383
      int mn = f >> 6, b = f & 63;
      g2t[f] = f2b(g2[b * 256 + mn]);
    }
  }
  {
    const int c4 = (t & 15) * 4;
    const int r  = t >> 4;
    #pragma unroll
    for (int p = 0; p < 4; ++p) {
      int rr = r + p * 16;
      *(ushort4*)&tile[rr][c4] = *(const ushort4*)&src[(long)(rb + rr) * 1024 + cb + c4];
    }
  }
  __syncthreads();
  {
    const int r4 = (t & 15) * 4;
    const int c  = t >> 4;
    #pragma unroll
    for (int p = 0; p < 4; ++p) {
      int cc = c + p * 16;
      ushort4 o;
      o.x = tile[r4 + 0][cc]; o.y = tile[r4 + 1][cc];
      o.z = tile[r4 + 2][cc]; o.w = tile[r4 + 3][cc];
      *(ushort4*)&dst[(long)(cb + cc) * 4096 + rb + r4] = o;
    }
  }
}

// ------------------------------------------------- fused V=Xbf@T1 then out=V@g2+bias
// Phase 1: m97-style K-loop, V-tile (128 rows x 128 lb-cols) in acc regs.
// Phase 2: V-tile -> LDS (bf16, row-major padded) -> MFMA vs g2t -> out 128x512 + bias.
// VSTRIDE=136: 128 cols + 8 pad; 136*2B=272B row pitch (16B-aligned, 4-bank rotation
// per row -> phase-2 short8 reads are 2-way = conflict-free).
#define VSTRIDE 136
__global__ __launch_bounds__(256, 2)
void gemm_fused(const uint16_t* __restrict__ A,    // Xbf 8192x4096
                const uint16_t* __restrict__ Bt,   // T1t 1024x4096 (k-contig)
                const uint16_t* __restrict__ g2t,  // 256x64 (k=b contig)
                const float* __restrict__ bias,
                float* __restrict__ out) {
  __shared__ __align__(16) uint16_t As[128 * 32];        // 8KB, no padding (global_load_lds)
  __shared__ __align__(16) uint16_t Bs[128 * 32];        // 8KB
  __shared__ __align__(16) uint16_t Vs[128 * VSTRIDE];   // 34KB

  const int bm = blockIdx.x * 128;
  const int bn = blockIdx.y * 128;      // V-col base: l0 = bn/64 = 2*blockIdx.y
  const int tid  = threadIdx.x;
  const int wave = tid >> 6;
  const int lane = tid & 63;
  const int wm = (wave >> 1) * 64;
  const int wn = (wave & 1) * 64;

  const uint16_t* Ab = A + (long)bm * 4096;
  const uint16_t* Bb = Bt + (long)bn * 4096;

  const int srow = lane >> 2;           // staging: 16 rows x 64B per wave-issue
  const int scol = (lane & 3) * 8;

  floatx4 acc[4][4];
  #pragma unroll
  for (int i = 0; i < 4; ++i)
    #pragma unroll
    for (int j = 0; j < 4; ++j)
      acc[i][j] = (floatx4){0.f, 0.f, 0.f, 0.f};

  const int fr = lane & 15;             // fragment row (m or n)
  const int fk = (lane >> 4) * 8;       // fragment k offset

  for (int k0 = 0; k0 < 4096; k0 += 32) {
    __syncthreads();
    #pragma unroll
    for (int t = 0; t < 2; ++t) {
      const int rblk = wave * 2 + t;    // 0..7, 16 rows each
      async_cp16(Ab + (long)(rblk * 16 + srow) * 4096 + k0 + scol, &As[rblk * 16 * 32]);
      async_cp16(Bb + (long)(rblk * 16 + srow) * 4096 + k0 + scol, &Bs[rblk * 16 * 32]);
    }
    __syncthreads();

    short8 af[4], bg[4];
    #pragma unroll
    for (int i = 0; i < 4; ++i)
      af[i] = *(const short8*)&As[(wm + i * 16 + fr) * 32 + fk];
    #pragma unroll
    for (int j = 0; j < 4; ++j)
      bg[j] = *(const short8*)&Bs[(wn + j * 16 + fr) * 32 + fk];

    #pragma unroll
    for (int i = 0; i < 4; ++i)
      #pragma unroll
      for (int j = 0; j < 4; ++j)
        acc[i][j] = __builtin_amdgcn_mfma_f32_16x16x32_bf16(af[i], bg[j], acc[i][j], 0, 0, 0);
  }

  // ---- phase-1 epilogue: acc (C-layout) -> Vs bf16 row-major [128][VSTRIDE]
  const int colq = lane & 15;
  const int rowq = (lane >> 4) * 4;
  __syncthreads();                       // last K-iter's LDS reads done (As/Bs reuse safety)
  #pragma unroll
  for (int i = 0; i < 4; ++i)
    #pragma unroll
    for (int j = 0; j < 4; ++j)
      #pragma unroll
      for (int r = 0; r < 4; ++r)
        Vs[(wm + i * 16 + rowq + r) * VSTRIDE + wn + j * 16 + colq] = f2b(acc[i][j][r]);
  __syncthreads();

  // ---- phase 2: out[row][l*256+mn] = sum_b Vs[row][(l-l0)*64+b] * g2t[mn][b] + bias
  // wave w: l = l0 + (w>>1), mn in [(w&1)*128, +128)
  const int bsel   = (wave >> 1) * 64;      // Vs col base (b-dim)
  const int mnBase = (wave & 1) * 128;      // g2t row base
  const long ocol0 = (long)blockIdx.y * 512 + (wave >> 1) * 256 + mnBase;

  short8 bg2[8][2];
  #pragma unroll
  for (int jn = 0; jn < 8; ++jn)
    #pragma unroll
    for (int ks = 0; ks < 2; ++ks)
      bg2[jn][ks] = *(const short8*)&g2t[(mnBase + jn * 16 + fr) * 64 + ks * 32 + fk];

  float bvs[8];
  #pragma unroll
  for (int jn = 0; jn < 8; ++jn)
    bvs[jn] = bias[ocol0 + jn * 16 + colq];

  #pragma unroll
  for (int pass = 0; pass < 4; ++pass) {
    floatx4 acc2[2][8];
    #pragma unroll
    for (int im = 0; im < 2; ++im)
      #pragma unroll
      for (int jn = 0; jn < 8; ++jn)
        acc2[im][jn] = (floatx4){0.f, 0.f, 0.f, 0.f};

    short8 af2[2][2];
    #pragma unroll
    for (int im = 0; im < 2; ++im)
      #pragma unroll
      for (int ks = 0; ks < 2; ++ks)
        af2[im][ks] = *(const short8*)&Vs[(pass * 32 + im * 16 + fr) * VSTRIDE + bsel + ks * 32 + fk];

    #pragma unroll
    for (int im = 0; im < 2; ++im)
      #pragma unroll
      for (int jn = 0; jn < 8; ++jn)
        #pragma unroll
        for (int ks = 0; ks < 2; ++ks)
          acc2[im][jn] = __builtin_amdgcn_mfma_f32_16x16x32_bf16(af2[im][ks], bg2[jn][ks], acc2[im][jn], 0, 0, 0);

    #pragma unroll
    for (int jn = 0; jn < 8; ++jn)
      #pragma unroll
      for (int im = 0; im < 2; ++im)
        #pragma unroll
        for (int r = 0; r < 4; ++r) {
          const int row = bm + pass * 32 + im * 16 + rowq + r;
          out[(long)row * 4096 + ocol0 + jn * 16 + colq] = acc2[im][jn][r] + bvs[jn];
        }
  }
}

// ---------------------------------------------------------------- launch
// ws layout (bytes): Xbf 64MB | T1 8MB | T1t 8MB | g2t 32KB  (~80MB)
static constexpr long XBF_OFF = 0;
static constexpr long T1_OFF  = 67108864;
static constexpr long T1T_OFF = 75497472;
static constexpr long G2T_OFF = 83886080;

extern "C" void kernel_launch(void* const* d_in, const int* in_sizes, int n_in,
                              void* d_out, int out_size, void* d_ws, size_t ws_size,
                              hipStream_t stream) {
  const float* x    = (const float*)d_in[0];
  const float* g0   = (const float*)d_in[1];
  const float* g1   = (const float*)d_in[2];
  const float* g2   = (const float*)d_in[3];
  const float* bias = (const float*)d_in[4];
  float* out = (float*)d_out;

  char* ws = (char*)d_ws;
  uint16_t* Xbf = (uint16_t*)(ws + XBF_OFF);
  uint16_t* T1  = (uint16_t*)(ws + T1_OFF);
  uint16_t* T1t = (uint16_t*)(ws + T1T_OFF);
  uint16_t* G2T = (uint16_t*)(ws + G2T_OFF);

  // 1) X -> bf16
  cvt_bf16<<<16384, 256, 0, stream>>>(x, Xbf);
  // 2) T1[(ijk)][(lb)] bf16, 4096x1024 row-major
  tt_t1<<<dim3(4, 128), 256, 0, stream>>>(g0, g1, T1);
  // 3) T1t = T1^T (1024x4096, k-contig) + g2t side-job
  transpose_t1<<<dim3(16, 64), 256, 0, stream>>>(T1, T1t, g2, G2T);
  // 4) fused: V = Xbf @ T1 (in-reg) then out = V @ g2 + bias
  gemm_fused<<<dim3(64, 8), 256, 0, stream>>>(Xbf, T1t, G2T, bias, out);
}